// Round 3
// baseline (498.991 us; speedup 1.0000x reference)
//
#include <hip/hip_runtime.h>
#include <stdint.h>

#define BB 4
#define TT 2048
#define DD 1024
#define NX (BB*TT*DD)          /* 8388608 x elements   */
#define NW (DD*DD)             /* 1048576 per W        */
#define SCALE 0.022097086912079608f   /* 1/sqrt(2048) */

typedef short v8s __attribute__((ext_vector_type(8)));
typedef float v4f __attribute__((ext_vector_type(4)));

typedef const void __attribute__((address_space(1))) *as1_cvp;
typedef void __attribute__((address_space(3))) *as3_vp;

__device__ __forceinline__ short f2bf(float f) {
    union { float f; uint32_t u; } x; x.f = f;
    uint32_t r = x.u + 0x7fffu + ((x.u >> 16) & 1u);   // RNE, finite inputs
    return (short)(r >> 16);
}
__device__ __forceinline__ float bf2f(short s) {
    union { uint32_t u; float f; } x; x.u = ((uint32_t)(uint16_t)s) << 16;
    return x.f;
}

// Async 16B global->LDS. lds dest must be wave-uniform base + lane*16.
__device__ __forceinline__ void gl_lds16(const short* g, const short* lds_wave_base) {
    __builtin_amdgcn_global_load_lds(
        (as1_cvp)(uintptr_t)(const void*)g,
        (as3_vp)(uint32_t)(uintptr_t)(const void*)lds_wave_base,
        16, 0, 0);
}

// ---- staging: rows x 64 shorts, XOR-8 chunk swizzle (row = 8 chunks = 32 banks)
__device__ __forceinline__ void stage_tile(const short* __restrict__ gsrc, int lda,
                                           short* lds, int tid) {     // 128 rows, 256 thr
    int wave = tid >> 6;
    #pragma unroll
    for (int is = 0; is < 4; is++) {
        int t = is * 256 + tid;          // 0..1023 : 16B chunk index
        int r = t >> 3, c = t & 7;
        int cg = c ^ (r & 7);            // swizzled global chunk
        const short* g = gsrc + (size_t)r * lda + cg * 8;
        const short* l = lds + is * 2048 + wave * 512;   // wave-uniform
        gl_lds16(g, l);
    }
}
__device__ __forceinline__ void stage_tile64(const short* __restrict__ gsrc, int lda,
                                             short* lds, int tid) {   // 64 rows, 256 thr
    int wave = tid >> 6;
    #pragma unroll
    for (int is = 0; is < 2; is++) {
        int t = is * 256 + tid;          // 0..511
        int r = t >> 3, c = t & 7;
        int cg = c ^ (r & 7);
        const short* g = gsrc + (size_t)r * lda + cg * 8;
        const short* l = lds + is * 2048 + wave * 512;
        gl_lds16(g, l);
    }
}
__device__ __forceinline__ v8s frag_read(const short* lds, int row, int cg) {
    return *(const v8s*)(lds + row * 64 + ((cg ^ (row & 7)) << 3));
}

// ---- 1024-thread staging for fused k_qkv (lda = 1024 shorts)
// A: 128 rows x 64 shorts (16 KB), 1 issue/thread
__device__ __forceinline__ void stA(const short* __restrict__ g, short* lds, int tid) {
    int r = tid >> 3, c = tid & 7, cg = c ^ (r & 7);
    gl_lds16(g + (size_t)r * 1024 + cg * 8, lds + (tid >> 6) * 512);
}
// B: 256 rows x 64 shorts (32 KB), 2 issues/thread
__device__ __forceinline__ void stB(const short* __restrict__ g, short* lds, int tid) {
    #pragma unroll
    for (int s = 0; s < 2; s++) {
        int t = s * 1024 + tid;
        int r = t >> 3, c = t & 7, cg = c ^ (r & 7);
        gl_lds16(g + (size_t)r * 1024 + cg * 8, lds + s * 8192 + (tid >> 6) * 512);
    }
}

// 64x128 tile compute (4 waves 2x2 of 32x64), acc[2][4]  (k_pk / k_pv)
#define COMPUTE_TILE64(Ac, Bc)                                                      \
    _Pragma("unroll")                                                               \
    for (int kk = 0; kk < 2; kk++) {                                                \
        v8s af[2], bf[4];                                                           \
        _Pragma("unroll")                                                           \
        for (int i = 0; i < 2; i++) af[i] = frag_read(Ac, wm + i*16 + lr, kk*4 + lq); \
        _Pragma("unroll")                                                           \
        for (int j = 0; j < 4; j++) bf[j] = frag_read(Bc, wn + j*16 + lr, kk*4 + lq); \
        _Pragma("unroll")                                                           \
        for (int i = 0; i < 2; i++)                                                 \
            _Pragma("unroll")                                                       \
            for (int j = 0; j < 4; j++)                                             \
                acc[i][j] = __builtin_amdgcn_mfma_f32_16x16x32_bf16(af[i], bf[j], acc[i][j], 0, 0, 0); \
    }

// ---------------------------------------------------------------- convert (+ rowsum init)
__global__ void k_convert(const float* __restrict__ x, const float* __restrict__ Wq,
                          const float* __restrict__ Wk, const float* __restrict__ Wv,
                          short* __restrict__ dst, float* __restrict__ rowsum) {
    int i = blockIdx.x * 256 + threadIdx.x;   // exactly (NX+3*NW)/4 threads
    if (i < BB * TT) rowsum[i] = (float)((15 - ((i & 2047) >> 7)) * 128);
    size_t base = (size_t)i * 4;
    const float* src; size_t off;
    if (base < NX)               { src = x;  off = base; }
    else if (base < NX + NW)     { src = Wq; off = base - NX; }
    else if (base < NX + 2*(size_t)NW) { src = Wk; off = base - NX - NW; }
    else                         { src = Wv; off = base - NX - 2*(size_t)NW; }
    float4 f = *(const float4*)(src + off);
    short4 h; h.x = f2bf(f.x); h.y = f2bf(f.y); h.z = f2bf(f.z); h.w = f2bf(f.w);
    *(short4*)(dst + base) = h;
}

// ---------------------------------------------------------------- fused QKV GEMM
// One block = (mtile 128 rows, ntile 256 cols) for ALL THREE weights: A staged once.
// 1024 threads = 16 waves (2M x 8N), per-wave 64x32 per which, acc 3x[4][2] v4f = 96 VGPR.
// LDS 128 KB: A dbuf 2x16K | B slots 3x32K (slot w holds B_w, rolling by K-tile).
// grid 256 = exactly 1 round (1 block/CU). K-loop rotated per mtile to de-synchronize
// same-address B reads across the 32 CUs of an XCD.
// Per K-tile: 3 phases (q,k,v). Phase = [ds_reads][stage issues][MFMA][counted vmcnt][bar].
// Ledger (per wave, A=1/B=2 issues): steady waits 3/3/2, never 0; issue->wait lead
// >= 1 full phase (~1300 cy) >> L2/L3 latency. Slot overwrite issues are always
// >= 1 barrier after the previous tenant's reads completed (reads are consumed by
// MFMA before the phase-end barrier).
__global__ __launch_bounds__(1024, 4) void k_qkv(const short* __restrict__ xb,
                                                 const short* __restrict__ wb,
                                                 short* __restrict__ q,
                                                 short* __restrict__ k,
                                                 short* __restrict__ vt) {
    int h = blockIdx.x;
    int w = (h & 7) * 32 + (h >> 3);          // bijective XCD swizzle (256 = 8*32)
    int ntile = w >> 6, mtile = w & 63;
    int m0 = mtile * 128, n0 = ntile * 256;
    int rot = mtile & 15;
    const short* Ag = xb + (size_t)m0 * 1024;
    const short* Bq = wb + (size_t)n0 * 1024;
    const short* Bk = wb + (size_t)NW + (size_t)n0 * 1024;
    const short* Bv = wb + 2 * (size_t)NW + (size_t)n0 * 1024;
    __shared__ __align__(16) short SH[65536];   // 128 KB
    short* SA0 = SH;                 // 8192 shorts
    short* SA1 = SH + 8192;
    short* SB0 = SH + 16384;         // 16384 shorts each
    short* SB1 = SH + 32768;
    short* SB2 = SH + 49152;
    int tid = threadIdx.x, lane = tid & 63, wave = tid >> 6;
    int wm2 = wave >> 3, wn8 = wave & 7;       // 2M x 8N
    int lr = lane & 15, lq = lane >> 4;
    int arow = wm2 * 64 + lr;                  // + i*16
    int brow = wn8 * 32 + lr;                  // + j*16
    v4f aq[4][2], ak[4][2], av[4][2];
    #pragma unroll
    for (int i = 0; i < 4; i++)
        #pragma unroll
        for (int j = 0; j < 2; j++) {
            aq[i][j] = (v4f){0.f, 0.f, 0.f, 0.f};
            ak[i][j] = (v4f){0.f, 0.f, 0.f, 0.f};
            av[i][j] = (v4f){0.f, 0.f, 0.f, 0.f};
        }

    // prologue: tile 0 (rotated): A(0), Bq(0), Bk(0)
    {
        int kt0 = rot;
        stA(Ag + kt0 * 64, SA0, tid);
        stB(Bq + kt0 * 64, SB0, tid);
        stB(Bk + kt0 * 64, SB1, tid);
    }
    asm volatile("s_waitcnt vmcnt(2)" ::: "memory");   // A(0)+Bq(0) landed
    __builtin_amdgcn_s_barrier();

    #pragma unroll 2
    for (int t = 0; t < 16; ++t) {
        short* SA  = (t & 1) ? SA1 : SA0;
        short* SAn = (t & 1) ? SA0 : SA1;
        int kt  = (t + rot) & 15;
        int ktn = (t + 1 + rot) & 15;
        v8s af[4][2], bf[2][2];
        // ================ phase 0 : Q ================
        #pragma unroll
        for (int i = 0; i < 4; i++)
            #pragma unroll
            for (int kk = 0; kk < 2; kk++) af[i][kk] = frag_read(SA, arow + i * 16, kk * 4 + lq);
        #pragma unroll
        for (int j = 0; j < 2; j++)
            #pragma unroll
            for (int kk = 0; kk < 2; kk++) bf[j][kk] = frag_read(SB0, brow + j * 16, kk * 4 + lq);
        stB(Bv + kt * 64, SB2, tid);                     // B(t,v) — always
        if (t < 15) stA(Ag + ktn * 64, SAn, tid);        // A(t+1)
        __builtin_amdgcn_s_setprio(1);
        #pragma unroll
        for (int kk = 0; kk < 2; kk++)
            #pragma unroll
            for (int i = 0; i < 4; i++)
                #pragma unroll
                for (int j = 0; j < 2; j++)
                    aq[i][j] = __builtin_amdgcn_mfma_f32_16x16x32_bf16(af[i][kk], bf[j][kk], aq[i][j], 0, 0, 0);
        __builtin_amdgcn_s_setprio(0);
        if (t < 15) { asm volatile("s_waitcnt vmcnt(3)" ::: "memory"); }   // Bk(t) landed
        else        { asm volatile("s_waitcnt vmcnt(2)" ::: "memory"); }
        __builtin_amdgcn_s_barrier();
        // ================ phase 1 : K ================
        #pragma unroll
        for (int j = 0; j < 2; j++)
            #pragma unroll
            for (int kk = 0; kk < 2; kk++) bf[j][kk] = frag_read(SB1, brow + j * 16, kk * 4 + lq);
        if (t < 15) stB(Bq + ktn * 64, SB0, tid);        // B(t+1,q)
        __builtin_amdgcn_s_setprio(1);
        #pragma unroll
        for (int kk = 0; kk < 2; kk++)
            #pragma unroll
            for (int i = 0; i < 4; i++)
                #pragma unroll
                for (int j = 0; j < 2; j++)
                    ak[i][j] = __builtin_amdgcn_mfma_f32_16x16x32_bf16(af[i][kk], bf[j][kk], ak[i][j], 0, 0, 0);
        __builtin_amdgcn_s_setprio(0);
        if (t < 15) { asm volatile("s_waitcnt vmcnt(3)" ::: "memory"); }   // Bv(t) landed
        else        { asm volatile("s_waitcnt vmcnt(0)" ::: "memory"); }
        __builtin_amdgcn_s_barrier();
        // ================ phase 2 : V ================
        #pragma unroll
        for (int j = 0; j < 2; j++)
            #pragma unroll
            for (int kk = 0; kk < 2; kk++) bf[j][kk] = frag_read(SB2, brow + j * 16, kk * 4 + lq);
        if (t < 15) stB(Bk + ktn * 64, SB1, tid);        // B(t+1,k)
        __builtin_amdgcn_s_setprio(1);
        #pragma unroll
        for (int kk = 0; kk < 2; kk++)
            #pragma unroll
            for (int i = 0; i < 4; i++)
                #pragma unroll
                for (int j = 0; j < 2; j++)
                    av[i][j] = __builtin_amdgcn_mfma_f32_16x16x32_bf16(af[i][kk], bf[j][kk], av[i][j], 0, 0, 0);
        __builtin_amdgcn_s_setprio(0);
        if (t < 15) {
            asm volatile("s_waitcnt vmcnt(2)" ::: "memory");   // A(t+1)+Bq(t+1) landed
            __builtin_amdgcn_s_barrier();
        }
    }

    // ---------------- epilogue: write q, k, vt
    #pragma unroll
    for (int i = 0; i < 4; i++)
        #pragma unroll
        for (int j = 0; j < 2; j++)
            #pragma unroll
            for (int r = 0; r < 4; r++) {
                int row = m0 + wm2 * 64 + i * 16 + lq * 4 + r;   // m = bb*2048 + t
                int col = n0 + wn8 * 32 + j * 16 + lr;           // e
                q[(size_t)row * 1024 + col] = f2bf(aq[i][j][r]);
                k[(size_t)row * 1024 + col] = f2bf(ak[i][j][r]);
                int bb = row >> 11, tt2 = row & 2047;
                vt[((size_t)bb << 21) + ((size_t)col << 11) + tt2] = f2bf(av[i][j][r]);
            }
}

// ---------------------------------------------------------------- tile suffix sums
__global__ void k_ts1(const short* __restrict__ vt, float* __restrict__ TSpart) {
    int g = blockIdx.x * 256 + threadIdx.x;           // 4*16*1024 threads
    int b = g >> 14, jt = (g >> 10) & 15, e = g & 1023;
    const short* row = vt + ((size_t)b << 21) + ((size_t)e << 11) + jt * 128;
    float s = 0.f;
    #pragma unroll
    for (int c = 0; c < 16; c++) {
        uint4 u = *(const uint4*)(row + c * 8);
        const short* hp = (const short*)&u;
        #pragma unroll
        for (int z = 0; z < 8; z++) s += bf2f(hp[z]);
    }
    TSpart[g] = s;   // [b][jt][e]
}
__global__ void k_ts2(const float* __restrict__ TSpart, float* __restrict__ TS) {
    int g = blockIdx.x * 256 + threadIdx.x;           // 4*1024 threads
    int b = g >> 10, e = g & 1023;
    float acc = 0.f;
    TS[(size_t)(b * 17 + 16) * 1024 + e] = 0.f;
    for (int jt = 15; jt >= 0; jt--) {
        acc += TSpart[(size_t)(b * 16 + jt) * 1024 + e];
        TS[(size_t)(b * 17 + jt) * 1024 + e] = acc;   // sum over j >= jt*128
    }
}

// ---------------------------------------------------------------- S -> P kernel (BM=64, dbuf, FULL UNROLL)
// grid.x = 272 (136 triangular pairs x 2 halves), big-qt first
__global__ __launch_bounds__(256, 3) void k_pk(const short* __restrict__ qm,
                                               const short* __restrict__ km,
                                               short* __restrict__ P,
                                               float* __restrict__ rowsum) {
    int flip = 271 - blockIdx.x, b = blockIdx.z;
    int half = flip & 1, pidx = flip >> 1;
    int qt = 0;
    while ((qt + 1) * (qt + 2) / 2 <= pidx) qt++;
    int kt = pidx - qt * (qt + 1) / 2;
    int r0 = qt * 128 + half * 64;                       // first q-row of this block
    const short* Ag = qm + ((size_t)b * 2048 + r0) * 1024;            // 64 rows
    const short* Bg = km + ((size_t)b * 2048 + (size_t)kt * 128) * 1024; // 128 rows
    __shared__ __align__(16) short SH[24576];            // A dbuf 2x8KB | B dbuf 2x16KB
    int tid = threadIdx.x, lane = tid & 63, wave = tid >> 6;
    int wm = (wave >> 1) * 32, wn = (wave & 1) * 64;
    int lr = lane & 15, lq = lane >> 4;
    v4f acc[2][4];
    for (int i = 0; i < 2; i++) for (int j = 0; j < 4; j++) acc[i][j] = (v4f){0.f,0.f,0.f,0.f};

    stage_tile64(Ag, 1024, SH, tid);
    stage_tile(Bg, 1024, SH + 8192, tid);
    #pragma unroll
    for (int it = 0; it < 16; ++it) {
        __syncthreads();
        short* Ac = SH + (it & 1) * 4096;
        short* Bc = SH + 8192 + (it & 1) * 8192;
        if (it + 1 < 16) {
            stage_tile64(Ag + (it + 1) * 64, 1024, SH + ((it + 1) & 1) * 4096, tid);
            stage_tile  (Bg + (it + 1) * 64, 1024, SH + 8192 + ((it + 1) & 1) * 8192, tid);
        }
        COMPUTE_TILE64(Ac, Bc);
    }
    short* Pb = P + ((size_t)b << 22);
    float rs[2][4];
    for (int i = 0; i < 2; i++) for (int r = 0; r < 4; r++) rs[i][r] = 0.f;
    #pragma unroll
    for (int i = 0; i < 2; i++)
        #pragma unroll
        for (int j = 0; j < 4; j++)
            #pragma unroll
            for (int r = 0; r < 4; r++) {
                int qi = r0 + wm + i*16 + lq*4 + r;
                int kj = kt * 128 + wn + j*16 + lr;
                float p = (kj <= qi) ? __expf(acc[i][j][r] * SCALE) : 1.0f;
                Pb[(size_t)qi * 2048 + kj] = f2bf(p);
                rs[i][r] += p;
            }
    #pragma unroll
    for (int m = 1; m < 16; m <<= 1)
        #pragma unroll
        for (int i = 0; i < 2; i++)
            #pragma unroll
            for (int r = 0; r < 4; r++) rs[i][r] += __shfl_xor(rs[i][r], m);
    if (lr == 0)
        #pragma unroll
        for (int i = 0; i < 2; i++)
            #pragma unroll
            for (int r = 0; r < 4; r++)
                atomicAdd(&rowsum[b * 2048 + r0 + wm + i*16 + lq*4 + r], rs[i][r]);
}

// ---------------------------------------------------------------- PV kernel (BM=64, paired qt, 34 iters, UNROLL 2)
// grid = (8 et, 16 = 8 pairs x 2 halves, 4 b): 512 uniform blocks
__global__ __launch_bounds__(256, 3) void k_pv(const short* __restrict__ P,
                                               const short* __restrict__ vt,
                                               const float* __restrict__ rowsum,
                                               const float* __restrict__ TS,
                                               float* __restrict__ out) {
    int et = blockIdx.x, p = blockIdx.y >> 1, half = blockIdx.y & 1, b = blockIdx.z;
    const short* Bg = vt + ((size_t)b << 21) + (size_t)et * 128 * 2048;  // 128 e-rows, ld 2048
    __shared__ __align__(16) short SH[24576];            // A dbuf 2x8KB | B dbuf 2x16KB
    int tid = threadIdx.x, lane = tid & 63, wave = tid >> 6;
    int wm = (wave >> 1) * 32, wn = (wave & 1) * 64;
    int lr = lane & 15, lq = lane >> 4;

    #pragma unroll
    for (int ph = 0; ph < 2; ph++) {
        int qt = ph ? p : 15 - p;              // iters: 2(16-p) + 2(p+1) = 34 for all blocks
        int r0 = qt * 128 + half * 64;
        int iters = 2 * (qt + 1);              // always even
        const short* Ag = P + ((size_t)b << 22) + (size_t)r0 * 2048;   // 64 rows, ld 2048
        v4f acc[2][4];
        for (int i = 0; i < 2; i++) for (int j = 0; j < 4; j++) acc[i][j] = (v4f){0.f,0.f,0.f,0.f};

        stage_tile64(Ag, 2048, SH, tid);
        stage_tile(Bg, 2048, SH + 8192, tid);
        for (int it = 0; it < iters; it += 2) {
            // ---- even sub-iter: buffers 0, prefetch into buffers 1
            __syncthreads();
            if (it + 1 < iters) {
                stage_tile64(Ag + (it + 1) * 64, 2048, SH + 4096, tid);
                stage_tile  (Bg + (it + 1) * 64, 2048, SH + 8192 + 8192, tid);
            }
            COMPUTE_TILE64(SH, SH + 8192);
            // ---- odd sub-iter: buffers 1, prefetch into buffers 0
            __syncthreads();
            if (it + 2 < iters) {
                stage_tile64(Ag + (it + 2) * 64, 2048, SH, tid);
                stage_tile  (Bg + (it + 2) * 64, 2048, SH + 8192, tid);
            }
            COMPUTE_TILE64(SH + 4096, SH + 8192 + 8192);
        }
        const float* tsrow = TS + (size_t)(b * 17 + qt + 1) * 1024;
        #pragma unroll
        for (int i = 0; i < 2; i++)
            #pragma unroll
            for (int j = 0; j < 4; j++)
                #pragma unroll
                for (int r = 0; r < 4; r++) {
                    int row = r0 + wm + i*16 + lq*4 + r;
                    int col = et * 128 + wn + j*16 + lr;
                    float o = (acc[i][j][r] + tsrow[col]) / rowsum[b * 2048 + row];
                    out[((size_t)(b * 2048 + row) << 10) + col] = o;
                }
        __syncthreads();   // protect LDS before next phase's initial staging
    }
}

// ---------------------------------------------------------------- launch
extern "C" void kernel_launch(void* const* d_in, const int* in_sizes, int n_in,
                              void* d_out, int out_size, void* d_ws, size_t ws_size,
                              hipStream_t stream) {
    const float* x  = (const float*)d_in[0];
    const float* Wq = (const float*)d_in[1];
    const float* Wk = (const float*)d_in[2];
    const float* Wv = (const float*)d_in[3];
    float* out = (float*)d_out;
    char* ws = (char*)d_ws;

    short* xb     = (short*)(ws + 0);            // 16,777,216 B
    short* wb     = (short*)(ws + 16777216);     //  6,291,456 B (Wq|Wk|Wv bf16)
    short* q      = (short*)(ws + 23068672);     // 16,777,216 B
    short* k      = (short*)(ws + 39845888);     // 16,777,216 B
    short* vt     = (short*)(ws + 56623104);     // 16,777,216 B  v transposed [b][e][t]
    short* P      = (short*)(ws + 73400320);     // 33,554,432 B
    float* rowsum = (float*)(ws + 106954752);    //     32,768 B
    float* TSpart = (float*)(ws + 106987520);    //    262,144 B
    float* TS     = (float*)(ws + 107249664);    //    278,528 B   total ~102.6 MB

    k_convert<<<11264, 256, 0, stream>>>(x, Wq, Wk, Wv, xb, rowsum);
    k_qkv<<<dim3(256, 1, 1), 1024, 0, stream>>>(xb, wb, q, k, vt);
    k_ts1<<<256, 256, 0, stream>>>(vt, TSpart);
    k_ts2<<<16, 256, 0, stream>>>(TSpart, TS);
    k_pk<<<dim3(272, 1, 4), 256, 0, stream>>>(q, k, P, rowsum);
    k_pv<<<dim3(8, 16, 4), 256, 0, stream>>>(P, vt, rowsum, TS, out);
}

// Round 4
// 237.329 us; speedup vs baseline: 2.1025x; 2.1025x over previous
//
#include <hip/hip_runtime.h>
#include <stdint.h>

#define BB 4
#define TT 2048
#define DD 1024
#define NX (BB*TT*DD)          /* 8388608 x elements   */
#define NW (DD*DD)             /* 1048576 per W        */
#define SCALE 0.022097086912079608f   /* 1/sqrt(2048) */

typedef short v8s __attribute__((ext_vector_type(8)));
typedef float v4f __attribute__((ext_vector_type(4)));

typedef const void __attribute__((address_space(1))) *as1_cvp;
typedef void __attribute__((address_space(3))) *as3_vp;

__device__ __forceinline__ short f2bf(float f) {
    union { float f; uint32_t u; } x; x.f = f;
    uint32_t r = x.u + 0x7fffu + ((x.u >> 16) & 1u);   // RNE, finite inputs
    return (short)(r >> 16);
}
__device__ __forceinline__ float bf2f(short s) {
    union { uint32_t u; float f; } x; x.u = ((uint32_t)(uint16_t)s) << 16;
    return x.f;
}

// Async 16B global->LDS. lds dest must be wave-uniform base + lane*16.
__device__ __forceinline__ void gl_lds16(const short* g, const short* lds_wave_base) {
    __builtin_amdgcn_global_load_lds(
        (as1_cvp)(uintptr_t)(const void*)g,
        (as3_vp)(uint32_t)(uintptr_t)(const void*)lds_wave_base,
        16, 0, 0);
}

__device__ __forceinline__ v8s frag_read(const short* lds, int row, int cg) {
    return *(const v8s*)(lds + row * 64 + ((cg ^ (row & 7)) << 3));
}

// ---- 512-thread staging: 128 rows x 64 shorts (16 KB), XOR-8 chunk swizzle, 2 issues
__device__ __forceinline__ void stage128_512(const short* __restrict__ g, int lda,
                                             short* lds, int tid) {
    #pragma unroll
    for (int s = 0; s < 2; s++) {
        int t = s * 512 + tid;           // 0..1023 : 16B chunk index
        int r = t >> 3, c = t & 7, cg = c ^ (r & 7);
        gl_lds16(g + (size_t)r * lda + cg * 8, lds + s * 4096 + (tid >> 6) * 512);
    }
}
// A for k_qkv: 128 rows x 64 shorts, lda 1024
__device__ __forceinline__ void stageA128(const short* __restrict__ g, short* lds, int tid) {
    stage128_512(g, 1024, lds, tid);
}
// B part p for k_qkv: idx-row = wn*32 + r holds global n-row wn*64 + p*32 + r (16 KB)
__device__ __forceinline__ void stageBpart(const short* __restrict__ g, short* lds,
                                           int tid, int p) {
    #pragma unroll
    for (int s = 0; s < 2; s++) {
        int t = s * 512 + tid;
        int r = t >> 3, c = t & 7, cg = c ^ (r & 7);
        int grow = ((r >> 5) << 6) + p * 32 + (r & 31);
        gl_lds16(g + (size_t)grow * 1024 + cg * 8, lds + s * 4096 + (tid >> 6) * 512);
    }
}

// ---------------------------------------------------------------- convert (+ rowsum init)
__global__ void k_convert(const float* __restrict__ x, const float* __restrict__ Wq,
                          const float* __restrict__ Wk, const float* __restrict__ Wv,
                          short* __restrict__ dst, float* __restrict__ rowsum) {
    int i = blockIdx.x * 256 + threadIdx.x;   // exactly (NX+3*NW)/4 threads
    if (i < BB * TT) rowsum[i] = (float)((15 - ((i & 2047) >> 7)) * 128);
    size_t base = (size_t)i * 4;
    const float* src; size_t off;
    if (base < NX)               { src = x;  off = base; }
    else if (base < NX + NW)     { src = Wq; off = base - NX; }
    else if (base < NX + 2*(size_t)NW) { src = Wk; off = base - NX - NW; }
    else                         { src = Wv; off = base - NX - 2*(size_t)NW; }
    float4 f = *(const float4*)(src + off);
    short4 h; h.x = f2bf(f.x); h.y = f2bf(f.y); h.z = f2bf(f.z); h.w = f2bf(f.w);
    *(short4*)(dst + base) = h;
}

// ---------------------------------------------------------------- QKV GEMM (round-2 verified, 63 us)
// BM=128, BN=256, BK=64, 8 waves (2M x 4N, per-wave 64x64), 768 blocks = 3 exact rounds.
// LDS 96 KB: 2 slots x (A 16K | Bpart0 16K | Bpart1 16K) -> 1 block/CU.
// Per K-tile: 2 phases of 16 MFMA/wave. Counted waits (never 0 in loop).
__global__ __launch_bounds__(512, 2) void k_qkv(const short* __restrict__ xb,
                                                const short* __restrict__ wb,
                                                short* __restrict__ q,
                                                short* __restrict__ k,
                                                short* __restrict__ vt) {
    int h = blockIdx.x;
    int w = (h & 7) * 96 + (h >> 3);          // bijective XCD swizzle (768 = 8*96)
    int which = w >> 8, rem = w & 255, ntile = rem >> 6, mtile = rem & 63;
    int m0 = mtile * 128, n0 = ntile * 256;
    const short* Ag = xb + (size_t)m0 * 1024;
    const short* Bg = wb + (size_t)which * NW + (size_t)n0 * 1024;
    __shared__ __align__(16) short SH[49152];   // 96 KB
    int tid = threadIdx.x, lane = tid & 63, wave = tid >> 6;
    int wm = wave >> 2, wn = wave & 3;          // 2M x 4N
    int lr = lane & 15, lq = lane >> 4;
    int arow = wm * 64 + lr;                    // + i*16
    int brow = wn * 32 + lr;                    // + jj*16 (part-local idx-row)
    v4f acc[4][4];
    #pragma unroll
    for (int i = 0; i < 4; i++)
        #pragma unroll
        for (int j = 0; j < 4; j++) acc[i][j] = (v4f){0.f, 0.f, 0.f, 0.f};

    // prologue: tile 0 into slot 0 (order A, Bp0, Bp1 so vmcnt(2) lands A+Bp0)
    stageA128 (Ag, SH,         tid);
    stageBpart(Bg, SH + 8192,  tid, 0);
    stageBpart(Bg, SH + 16384, tid, 1);

    #pragma unroll
    for (int t = 0; t < 16; ++t) {
        short* S  = SH + (t & 1) * 24576;
        short* Sn = SH + ((t + 1) & 1) * 24576;
        const short* Agn = Ag + (t + 1) * 64;
        const short* Bgn = Bg + (t + 1) * 64;
        // ---------------- phase 1: acc[*][0..1]  (A + B part0)
        asm volatile("s_waitcnt vmcnt(2)" ::: "memory");
        __builtin_amdgcn_s_barrier();
        v8s af[4][2], bf[2][2];
        #pragma unroll
        for (int i = 0; i < 4; i++)
            #pragma unroll
            for (int kk = 0; kk < 2; kk++) af[i][kk] = frag_read(S, arow + i * 16, kk * 4 + lq);
        #pragma unroll
        for (int jj = 0; jj < 2; jj++)
            #pragma unroll
            for (int kk = 0; kk < 2; kk++) bf[jj][kk] = frag_read(S + 8192, brow + jj * 16, kk * 4 + lq);
        if (t < 15) {
            stageA128 (Agn, Sn,        tid);
            stageBpart(Bgn, Sn + 8192, tid, 0);
        }
        __builtin_amdgcn_s_setprio(1);
        #pragma unroll
        for (int kk = 0; kk < 2; kk++)
            #pragma unroll
            for (int i = 0; i < 4; i++)
                #pragma unroll
                for (int jj = 0; jj < 2; jj++)
                    acc[i][jj] = __builtin_amdgcn_mfma_f32_16x16x32_bf16(af[i][kk], bf[jj][kk], acc[i][jj], 0, 0, 0);
        __builtin_amdgcn_s_setprio(0);
        // ---------------- phase 2: acc[*][2..3]  (B part1)
        if (t < 15) { asm volatile("s_waitcnt vmcnt(4)" ::: "memory"); }
        else        { asm volatile("s_waitcnt vmcnt(0)" ::: "memory"); }
        __builtin_amdgcn_s_barrier();
        v8s bg2[2][2];
        #pragma unroll
        for (int jj = 0; jj < 2; jj++)
            #pragma unroll
            for (int kk = 0; kk < 2; kk++) bg2[jj][kk] = frag_read(S + 16384, brow + jj * 16, kk * 4 + lq);
        if (t < 15) stageBpart(Bgn, Sn + 16384, tid, 1);
        __builtin_amdgcn_s_setprio(1);
        #pragma unroll
        for (int kk = 0; kk < 2; kk++)
            #pragma unroll
            for (int i = 0; i < 4; i++)
                #pragma unroll
                for (int jj = 0; jj < 2; jj++)
                    acc[i][2 + jj] = __builtin_amdgcn_mfma_f32_16x16x32_bf16(af[i][kk], bg2[jj][kk], acc[i][2 + jj], 0, 0, 0);
        __builtin_amdgcn_s_setprio(0);
    }

    // ---------------- epilogue
    if (which == 2) {
        #pragma unroll
        for (int a = 0; a < 4; a++)
            #pragma unroll
            for (int b = 0; b < 4; b++)
                #pragma unroll
                for (int r = 0; r < 4; r++) {
                    int row = m0 + wm * 64 + a * 16 + lq * 4 + r;   // m = bb*2048 + t
                    int col = n0 + wn * 64 + b * 16 + lr;           // e
                    int bb = row >> 11, tt2 = row & 2047;
                    vt[((size_t)bb << 21) + ((size_t)col << 11) + tt2] = f2bf(acc[a][b][r]);
                }
    } else {
        short* outp = (which == 0) ? q : k;
        #pragma unroll
        for (int a = 0; a < 4; a++)
            #pragma unroll
            for (int b = 0; b < 4; b++)
                #pragma unroll
                for (int r = 0; r < 4; r++) {
                    int row = m0 + wm * 64 + a * 16 + lq * 4 + r;
                    int col = n0 + wn * 64 + b * 16 + lr;
                    outp[(size_t)row * 1024 + col] = f2bf(acc[a][b][r]);
                }
    }
}

// ---------------------------------------------------------------- tile suffix sums
__global__ void k_ts1(const short* __restrict__ vt, float* __restrict__ TSpart) {
    int g = blockIdx.x * 256 + threadIdx.x;           // 4*16*1024 threads
    int b = g >> 14, jt = (g >> 10) & 15, e = g & 1023;
    const short* row = vt + ((size_t)b << 21) + ((size_t)e << 11) + jt * 128;
    float s = 0.f;
    #pragma unroll
    for (int c = 0; c < 16; c++) {
        uint4 u = *(const uint4*)(row + c * 8);
        const short* hp = (const short*)&u;
        #pragma unroll
        for (int z = 0; z < 8; z++) s += bf2f(hp[z]);
    }
    TSpart[g] = s;   // [b][jt][e]
}
__global__ void k_ts2(const float* __restrict__ TSpart, float* __restrict__ TS) {
    int g = blockIdx.x * 256 + threadIdx.x;           // 4*1024 threads
    int b = g >> 10, e = g & 1023;
    float acc = 0.f;
    TS[(size_t)(b * 17 + 16) * 1024 + e] = 0.f;
    for (int jt = 15; jt >= 0; jt--) {
        acc += TSpart[(size_t)(b * 16 + jt) * 1024 + e];
        TS[(size_t)(b * 17 + jt) * 1024 + e] = acc;   // sum over j >= jt*128
    }
}

// ---------------------------------------------------------------- S -> P kernel
// BM=128 (full qt) x BN=128 (one kt), 512 thr / 8 waves (2M x 4N, per-wave 64x32).
// grid (136 triangular pairs, 1, 4 b) = 544 equal blocks; LDS 64 KB -> 2 blocks/CU.
__global__ __launch_bounds__(512, 4) void k_pk(const short* __restrict__ qm,
                                               const short* __restrict__ km,
                                               short* __restrict__ P,
                                               float* __restrict__ rowsum) {
    int pidx = blockIdx.x, b = blockIdx.z;
    int qt = 0;
    while ((qt + 1) * (qt + 2) / 2 <= pidx) qt++;
    int kt = pidx - qt * (qt + 1) / 2;
    int r0 = qt * 128;
    const short* Ag = qm + ((size_t)b * 2048 + r0) * 1024;               // 128 q-rows
    const short* Bg = km + ((size_t)b * 2048 + (size_t)kt * 128) * 1024; // 128 k-rows
    __shared__ __align__(16) short SH[32768];   // A dbuf 2x16KB | B dbuf 2x16KB
    int tid = threadIdx.x, lane = tid & 63, wave = tid >> 6;
    int wm2 = wave >> 2, wn4 = wave & 3;
    int lr = lane & 15, lq = lane >> 4;
    v4f acc[4][2];
    #pragma unroll
    for (int i = 0; i < 4; i++)
        #pragma unroll
        for (int j = 0; j < 2; j++) acc[i][j] = (v4f){0.f, 0.f, 0.f, 0.f};

    stage128_512(Ag, 1024, SH, tid);
    stage128_512(Bg, 1024, SH + 16384, tid);
    #pragma unroll
    for (int it = 0; it < 16; ++it) {
        __syncthreads();
        short* Ac = SH + (it & 1) * 8192;
        short* Bc = SH + 16384 + (it & 1) * 8192;
        if (it + 1 < 16) {
            stage128_512(Ag + (it + 1) * 64, 1024, SH + ((it + 1) & 1) * 8192, tid);
            stage128_512(Bg + (it + 1) * 64, 1024, SH + 16384 + ((it + 1) & 1) * 8192, tid);
        }
        v8s af[4][2], bf[2][2];
        #pragma unroll
        for (int i = 0; i < 4; i++)
            #pragma unroll
            for (int kk = 0; kk < 2; kk++) af[i][kk] = frag_read(Ac, wm2 * 64 + i * 16 + lr, kk * 4 + lq);
        #pragma unroll
        for (int j = 0; j < 2; j++)
            #pragma unroll
            for (int kk = 0; kk < 2; kk++) bf[j][kk] = frag_read(Bc, wn4 * 32 + j * 16 + lr, kk * 4 + lq);
        __builtin_amdgcn_s_setprio(1);
        #pragma unroll
        for (int kk = 0; kk < 2; kk++)
            #pragma unroll
            for (int i = 0; i < 4; i++)
                #pragma unroll
                for (int j = 0; j < 2; j++)
                    acc[i][j] = __builtin_amdgcn_mfma_f32_16x16x32_bf16(af[i][kk], bf[j][kk], acc[i][j], 0, 0, 0);
        __builtin_amdgcn_s_setprio(0);
    }
    short* Pb = P + ((size_t)b << 22);
    float rs[4][4];
    #pragma unroll
    for (int i = 0; i < 4; i++)
        #pragma unroll
        for (int r = 0; r < 4; r++) rs[i][r] = 0.f;
    #pragma unroll
    for (int i = 0; i < 4; i++)
        #pragma unroll
        for (int j = 0; j < 2; j++)
            #pragma unroll
            for (int r = 0; r < 4; r++) {
                int qi = r0 + wm2 * 64 + i * 16 + lq * 4 + r;
                int kj = kt * 128 + wn4 * 32 + j * 16 + lr;
                float p = (kj <= qi) ? __expf(acc[i][j][r] * SCALE) : 1.0f;
                Pb[(size_t)qi * 2048 + kj] = f2bf(p);
                rs[i][r] += p;
            }
    #pragma unroll
    for (int m = 1; m < 16; m <<= 1)
        #pragma unroll
        for (int i = 0; i < 4; i++)
            #pragma unroll
            for (int r = 0; r < 4; r++) rs[i][r] += __shfl_xor(rs[i][r], m);
    if (lr == 0)
        #pragma unroll
        for (int i = 0; i < 4; i++)
            #pragma unroll
            for (int r = 0; r < 4; r++)
                atomicAdd(&rowsum[b * 2048 + r0 + wm2 * 64 + i * 16 + lq * 4 + r], rs[i][r]);
}

// ---------------------------------------------------------------- PV kernel
// BM=128 (full qt) x 128 e-cols, 512 thr / 8 waves (2M x 4N). Paired qt: ph0 = 15-p,
// ph1 = p -> 34 BK-64 steps for every block. grid (8 et, 8 p, 4 b) = 256 = 1 exact round.
__global__ __launch_bounds__(512, 4) void k_pv(const short* __restrict__ P,
                                               const short* __restrict__ vt,
                                               const float* __restrict__ rowsum,
                                               const float* __restrict__ TS,
                                               float* __restrict__ out) {
    int et = blockIdx.x, p = blockIdx.y, b = blockIdx.z;
    const short* Bg = vt + ((size_t)b << 21) + (size_t)et * 128 * 2048;  // 128 e-rows, ld 2048
    __shared__ __align__(16) short SH[32768];   // A dbuf 2x16KB | B dbuf 2x16KB
    int tid = threadIdx.x, lane = tid & 63, wave = tid >> 6;
    int wm2 = wave >> 2, wn4 = wave & 3;
    int lr = lane & 15, lq = lane >> 4;

    #pragma unroll
    for (int ph = 0; ph < 2; ph++) {
        int qt = ph ? p : 15 - p;
        int r0 = qt * 128;
        int iters = 2 * (qt + 1);              // BK-64 steps
        const short* Ag = P + ((size_t)b << 22) + (size_t)r0 * 2048;   // 128 rows, ld 2048
        v4f acc[4][2];
        #pragma unroll
        for (int i = 0; i < 4; i++)
            #pragma unroll
            for (int j = 0; j < 2; j++) acc[i][j] = (v4f){0.f, 0.f, 0.f, 0.f};

        stage128_512(Ag, 2048, SH, tid);
        stage128_512(Bg, 2048, SH + 16384, tid);
        for (int it = 0; it < iters; ++it) {
            __syncthreads();
            short* Ac = SH + (it & 1) * 8192;
            short* Bc = SH + 16384 + (it & 1) * 8192;
            if (it + 1 < iters) {
                stage128_512(Ag + (it + 1) * 64, 2048, SH + ((it + 1) & 1) * 8192, tid);
                stage128_512(Bg + (it + 1) * 64, 2048, SH + 16384 + ((it + 1) & 1) * 8192, tid);
            }
            v8s af[4][2], bf[2][2];
            #pragma unroll
            for (int i = 0; i < 4; i++)
                #pragma unroll
                for (int kk = 0; kk < 2; kk++) af[i][kk] = frag_read(Ac, wm2 * 64 + i * 16 + lr, kk * 4 + lq);
            #pragma unroll
            for (int j = 0; j < 2; j++)
                #pragma unroll
                for (int kk = 0; kk < 2; kk++) bf[j][kk] = frag_read(Bc, wn4 * 32 + j * 16 + lr, kk * 4 + lq);
            __builtin_amdgcn_s_setprio(1);
            #pragma unroll
            for (int kk = 0; kk < 2; kk++)
                #pragma unroll
                for (int i = 0; i < 4; i++)
                    #pragma unroll
                    for (int j = 0; j < 2; j++)
                        acc[i][j] = __builtin_amdgcn_mfma_f32_16x16x32_bf16(af[i][kk], bf[j][kk], acc[i][j], 0, 0, 0);
            __builtin_amdgcn_s_setprio(0);
        }
        const float* tsrow = TS + (size_t)(b * 17 + qt + 1) * 1024;
        #pragma unroll
        for (int i = 0; i < 4; i++)
            #pragma unroll
            for (int j = 0; j < 2; j++)
                #pragma unroll
                for (int r = 0; r < 4; r++) {
                    int row = r0 + wm2 * 64 + i * 16 + lq * 4 + r;
                    int col = et * 128 + wn4 * 32 + j * 16 + lr;
                    float o = (acc[i][j][r] + tsrow[col]) / rowsum[b * 2048 + row];
                    out[((size_t)(b * 2048 + row) << 10) + col] = o;
                }
        __syncthreads();   // protect LDS before next phase's initial staging
    }
}

// ---------------------------------------------------------------- launch
extern "C" void kernel_launch(void* const* d_in, const int* in_sizes, int n_in,
                              void* d_out, int out_size, void* d_ws, size_t ws_size,
                              hipStream_t stream) {
    const float* x  = (const float*)d_in[0];
    const float* Wq = (const float*)d_in[1];
    const float* Wk = (const float*)d_in[2];
    const float* Wv = (const float*)d_in[3];
    float* out = (float*)d_out;
    char* ws = (char*)d_ws;

    short* xb     = (short*)(ws + 0);            // 16,777,216 B
    short* wb     = (short*)(ws + 16777216);     //  6,291,456 B (Wq|Wk|Wv bf16)
    short* q      = (short*)(ws + 23068672);     // 16,777,216 B
    short* k      = (short*)(ws + 39845888);     // 16,777,216 B
    short* vt     = (short*)(ws + 56623104);     // 16,777,216 B  v transposed [b][e][t]
    short* P      = (short*)(ws + 73400320);     // 33,554,432 B
    float* rowsum = (float*)(ws + 106954752);    //     32,768 B
    float* TSpart = (float*)(ws + 106987520);    //    262,144 B
    float* TS     = (float*)(ws + 107249664);    //    278,528 B   total ~102.6 MB

    k_convert<<<11264, 256, 0, stream>>>(x, Wq, Wk, Wv, xb, rowsum);
    k_qkv<<<dim3(768, 1, 1), 512, 0, stream>>>(xb, wb, q, k, vt);
    k_ts1<<<256, 256, 0, stream>>>(vt, TSpart);
    k_ts2<<<16, 256, 0, stream>>>(TSpart, TS);
    k_pk<<<dim3(136, 1, 4), 512, 0, stream>>>(q, k, P, rowsum);
    k_pv<<<dim3(8, 8, 4), 512, 0, stream>>>(P, vt, rowsum, TS, out);
}

// Round 5
// 229.691 us; speedup vs baseline: 2.1724x; 1.0333x over previous
//
#include <hip/hip_runtime.h>
#include <stdint.h>

#define BB 4
#define TT 2048
#define DD 1024
#define NX (BB*TT*DD)          /* 8388608 x elements   */
#define NW (DD*DD)             /* 1048576 per W        */
#define SCALE 0.022097086912079608f   /* 1/sqrt(2048) */

typedef short v8s __attribute__((ext_vector_type(8)));
typedef float v4f __attribute__((ext_vector_type(4)));

typedef const void __attribute__((address_space(1))) *as1_cvp;
typedef void __attribute__((address_space(3))) *as3_vp;

__device__ __forceinline__ short f2bf(float f) {
    union { float f; uint32_t u; } x; x.f = f;
    uint32_t r = x.u + 0x7fffu + ((x.u >> 16) & 1u);   // RNE, finite inputs
    return (short)(r >> 16);
}
__device__ __forceinline__ float bf2f(short s) {
    union { uint32_t u; float f; } x; x.u = ((uint32_t)(uint16_t)s) << 16;
    return x.f;
}

// Async 16B global->LDS. lds dest must be wave-uniform base + lane*16.
__device__ __forceinline__ void gl_lds16(const short* g, const short* lds_wave_base) {
    __builtin_amdgcn_global_load_lds(
        (as1_cvp)(uintptr_t)(const void*)g,
        (as3_vp)(uint32_t)(uintptr_t)(const void*)lds_wave_base,
        16, 0, 0);
}

__device__ __forceinline__ v8s frag_read(const short* lds, int row, int cg) {
    return *(const v8s*)(lds + row * 64 + ((cg ^ (row & 7)) << 3));
}

#define WAITV(N) asm volatile("s_waitcnt vmcnt(" #N ")" ::: "memory")

// ---- 256-thread staging: rows x 64 shorts, XOR-8 chunk swizzle
__device__ __forceinline__ void stage_tile(const short* __restrict__ gsrc, int lda,
                                           short* lds, int tid) {     // 128 rows
    int wave = tid >> 6;
    #pragma unroll
    for (int is = 0; is < 4; is++) {
        int t = is * 256 + tid;          // 0..1023 : 16B chunk index
        int r = t >> 3, c = t & 7;
        int cg = c ^ (r & 7);
        const short* g = gsrc + (size_t)r * lda + cg * 8;
        const short* l = lds + is * 2048 + wave * 512;   // wave-uniform
        gl_lds16(g, l);
    }
}
__device__ __forceinline__ void stage_tile64(const short* __restrict__ gsrc, int lda,
                                             short* lds, int tid) {   // 64 rows
    int wave = tid >> 6;
    #pragma unroll
    for (int is = 0; is < 2; is++) {
        int t = is * 256 + tid;          // 0..511
        int r = t >> 3, c = t & 7;
        int cg = c ^ (r & 7);
        const short* g = gsrc + (size_t)r * lda + cg * 8;
        const short* l = lds + is * 2048 + wave * 512;
        gl_lds16(g, l);
    }
}

// ---- 512-thread staging for k_qkv (lda = 1024)
__device__ __forceinline__ void stageA128(const short* __restrict__ g, short* lds, int tid) {
    #pragma unroll
    for (int s = 0; s < 2; s++) {
        int t = s * 512 + tid;           // 0..1023
        int r = t >> 3, c = t & 7, cg = c ^ (r & 7);
        gl_lds16(g + (size_t)r * 1024 + cg * 8, lds + s * 4096 + (tid >> 6) * 512);
    }
}
// B part p: idx-row = wn*32 + r holds global n-row wn*64 + p*32 + r (16 KB)
__device__ __forceinline__ void stageBpart(const short* __restrict__ g, short* lds,
                                           int tid, int p) {
    #pragma unroll
    for (int s = 0; s < 2; s++) {
        int t = s * 512 + tid;
        int r = t >> 3, c = t & 7, cg = c ^ (r & 7);
        int grow = ((r >> 5) << 6) + p * 32 + (r & 31);
        gl_lds16(g + (size_t)grow * 1024 + cg * 8, lds + s * 4096 + (tid >> 6) * 512);
    }
}

// 64x128 tile compute (4 waves 2x2 of 32x64), acc[2][4]  (k_pk / k_pv)
#define COMPUTE_TILE64(Ac, Bc)                                                      \
    _Pragma("unroll")                                                               \
    for (int kk = 0; kk < 2; kk++) {                                                \
        v8s af[2], bf[4];                                                           \
        _Pragma("unroll")                                                           \
        for (int i = 0; i < 2; i++) af[i] = frag_read(Ac, wm + i*16 + lr, kk*4 + lq); \
        _Pragma("unroll")                                                           \
        for (int j = 0; j < 4; j++) bf[j] = frag_read(Bc, wn + j*16 + lr, kk*4 + lq); \
        _Pragma("unroll")                                                           \
        for (int i = 0; i < 2; i++)                                                 \
            _Pragma("unroll")                                                       \
            for (int j = 0; j < 4; j++)                                             \
                acc[i][j] = __builtin_amdgcn_mfma_f32_16x16x32_bf16(af[i], bf[j], acc[i][j], 0, 0, 0); \
    }

// ---------------------------------------------------------------- convert (+ rowsum init)
__global__ void k_convert(const float* __restrict__ x, const float* __restrict__ Wq,
                          const float* __restrict__ Wk, const float* __restrict__ Wv,
                          short* __restrict__ dst, float* __restrict__ rowsum) {
    int i = blockIdx.x * 256 + threadIdx.x;   // exactly (NX+3*NW)/4 threads
    if (i < BB * TT) rowsum[i] = (float)((15 - ((i & 2047) >> 7)) * 128);
    size_t base = (size_t)i * 4;
    const float* src; size_t off;
    if (base < NX)               { src = x;  off = base; }
    else if (base < NX + NW)     { src = Wq; off = base - NX; }
    else if (base < NX + 2*(size_t)NW) { src = Wk; off = base - NX - NW; }
    else                         { src = Wv; off = base - NX - 2*(size_t)NW; }
    float4 f = *(const float4*)(src + off);
    short4 h; h.x = f2bf(f.x); h.y = f2bf(f.y); h.z = f2bf(f.z); h.w = f2bf(f.w);
    *(short4*)(dst + base) = h;
}

// ---------------------------------------------------------------- QKV GEMM (triple-buffered)
// BM=128, BN=256, BK=64, 8 waves (2M x 4N), 768 blocks = 3 exact rounds, 1 blk/CU.
// LDS 144 KB: 3 slots x (A 16K | Bp0 16K | Bp1 16K). Per-thread issue sequence:
//   P1(t): [wait vmcnt, bar, ds_read A,Bp0, issue Bp1(t+2), MFMA]
//   P2(t): [wait vmcnt, bar, ds_read Bp1,  issue A,Bp0(t+3), MFMA]
// Steady waits 12/12 (tail 8/6, 2/0) -> lead 2-2.5 K-tiles (~6000 cy) >> HBM latency,
// never drains. Slot safety: t+3 A/Bp0 issued after P2(t) barrier (all A/Bp0(t) reads
// done); Bp1(t+2) after P1(t) barrier (all Bp1(t-1) reads done).
// K-rotation rot=(mtile+4*ntile+5*which)&15 de-synchronizes panel-sharing CUs.
__global__ __launch_bounds__(512, 2) void k_qkv(const short* __restrict__ xb,
                                                const short* __restrict__ wb,
                                                short* __restrict__ q,
                                                short* __restrict__ k,
                                                short* __restrict__ vt) {
    int h = blockIdx.x;
    int w = (h & 7) * 96 + (h >> 3);          // bijective XCD swizzle (768 = 8*96)
    int which = w >> 8, rem = w & 255, ntile = rem >> 6, mtile = rem & 63;
    int m0 = mtile * 128, n0 = ntile * 256;
    int rot = (mtile + 4 * ntile + 5 * which) & 15;
    const short* Ag = xb + (size_t)m0 * 1024;
    const short* Bg = wb + (size_t)which * NW + (size_t)n0 * 1024;
    __shared__ __align__(16) short SH[73728];   // 144 KB = 3 x 24576 shorts
    int tid = threadIdx.x, lane = tid & 63, wave = tid >> 6;
    int wm = wave >> 2, wn = wave & 3;          // 2M x 4N
    int lr = lane & 15, lq = lane >> 4;
    int arow = wm * 64 + lr;                    // + i*16
    int brow = wn * 32 + lr;                    // + jj*16 (part-local idx-row)
    v4f acc[4][4];
    #pragma unroll
    for (int i = 0; i < 4; i++)
        #pragma unroll
        for (int j = 0; j < 4; j++) acc[i][j] = (v4f){0.f, 0.f, 0.f, 0.f};

    // prologue: tiles 0,1,2 (A,Bp0,Bp1 each) in exact ledger order
    #pragma unroll
    for (int t = 0; t < 3; ++t) {
        int kt = (t + rot) & 15;
        short* S = SH + t * 24576;
        stageA128 (Ag + kt * 64, S,         tid);
        stageBpart(Bg + kt * 64, S + 8192,  tid, 0);
        if (t < 2) stageBpart(Bg + kt * 64, S + 16384, tid, 1);
    }
    // outstanding/thread: 16  (A0,B00,B10, A1,B01,B11, A2,B02)

    #pragma unroll
    for (int t = 0; t < 16; ++t) {
        short* S = SH + (t % 3) * 24576;
        // ---------------- phase 1: acc[*][0..1]  (A + B part0)
        if (t <= 13)      { WAITV(12); }
        else if (t == 14) { WAITV(8);  }
        else              { WAITV(2);  }
        __builtin_amdgcn_s_barrier();
        v8s af[4][2], bf[2][2];
        #pragma unroll
        for (int i = 0; i < 4; i++)
            #pragma unroll
            for (int kk = 0; kk < 2; kk++) af[i][kk] = frag_read(S, arow + i * 16, kk * 4 + lq);
        #pragma unroll
        for (int jj = 0; jj < 2; jj++)
            #pragma unroll
            for (int kk = 0; kk < 2; kk++) bf[jj][kk] = frag_read(S + 8192, brow + jj * 16, kk * 4 + lq);
        if (t + 2 <= 15) {   // Bp1(t+2) -> slot (t+2)%3 (tile t-1's Bp1 fully read)
            int kt2 = (t + 2 + rot) & 15;
            stageBpart(Bg + kt2 * 64, SH + ((t + 2) % 3) * 24576 + 16384, tid, 1);
        }
        __builtin_amdgcn_s_setprio(1);
        #pragma unroll
        for (int kk = 0; kk < 2; kk++)
            #pragma unroll
            for (int i = 0; i < 4; i++)
                #pragma unroll
                for (int jj = 0; jj < 2; jj++)
                    acc[i][jj] = __builtin_amdgcn_mfma_f32_16x16x32_bf16(af[i][kk], bf[jj][kk], acc[i][jj], 0, 0, 0);
        __builtin_amdgcn_s_setprio(0);
        // ---------------- phase 2: acc[*][2..3]  (B part1)
        if (t <= 13)      { WAITV(12); }
        else if (t == 14) { WAITV(6);  }
        else              { WAITV(0);  }
        __builtin_amdgcn_s_barrier();
        v8s bg2[2][2];
        #pragma unroll
        for (int jj = 0; jj < 2; jj++)
            #pragma unroll
            for (int kk = 0; kk < 2; kk++) bg2[jj][kk] = frag_read(S + 16384, brow + jj * 16, kk * 4 + lq);
        if (t + 3 <= 15) {   // A,Bp0(t+3) -> slot t%3 (tile t's A/Bp0 fully read)
            int kt3 = (t + 3 + rot) & 15;
            short* Sn = SH + (t % 3) * 24576;
            stageA128 (Ag + kt3 * 64, Sn,        tid);
            stageBpart(Bg + kt3 * 64, Sn + 8192, tid, 0);
        }
        __builtin_amdgcn_s_setprio(1);
        #pragma unroll
        for (int kk = 0; kk < 2; kk++)
            #pragma unroll
            for (int i = 0; i < 4; i++)
                #pragma unroll
                for (int jj = 0; jj < 2; jj++)
                    acc[i][2 + jj] = __builtin_amdgcn_mfma_f32_16x16x32_bf16(af[i][kk], bg2[jj][kk], acc[i][2 + jj], 0, 0, 0);
        __builtin_amdgcn_s_setprio(0);
    }

    // ---------------- epilogue
    if (which == 2) {
        #pragma unroll
        for (int a = 0; a < 4; a++)
            #pragma unroll
            for (int b = 0; b < 4; b++)
                #pragma unroll
                for (int r = 0; r < 4; r++) {
                    int row = m0 + wm * 64 + a * 16 + lq * 4 + r;   // m = bb*2048 + t
                    int col = n0 + wn * 64 + b * 16 + lr;           // e
                    int bb = row >> 11, tt2 = row & 2047;
                    vt[((size_t)bb << 21) + ((size_t)col << 11) + tt2] = f2bf(acc[a][b][r]);
                }
    } else {
        short* outp = (which == 0) ? q : k;
        #pragma unroll
        for (int a = 0; a < 4; a++)
            #pragma unroll
            for (int b = 0; b < 4; b++)
                #pragma unroll
                for (int r = 0; r < 4; r++) {
                    int row = m0 + wm * 64 + a * 16 + lq * 4 + r;
                    int col = n0 + wn * 64 + b * 16 + lr;
                    outp[(size_t)row * 1024 + col] = f2bf(acc[a][b][r]);
                }
    }
}

// ---------------------------------------------------------------- tile suffix sums
__global__ void k_ts1(const short* __restrict__ vt, float* __restrict__ TSpart) {
    int g = blockIdx.x * 256 + threadIdx.x;           // 4*16*1024 threads
    int b = g >> 14, jt = (g >> 10) & 15, e = g & 1023;
    const short* row = vt + ((size_t)b << 21) + ((size_t)e << 11) + jt * 128;
    float s = 0.f;
    #pragma unroll
    for (int c = 0; c < 16; c++) {
        uint4 u = *(const uint4*)(row + c * 8);
        const short* hp = (const short*)&u;
        #pragma unroll
        for (int z = 0; z < 8; z++) s += bf2f(hp[z]);
    }
    TSpart[g] = s;   // [b][jt][e]
}
__global__ void k_ts2(const float* __restrict__ TSpart, float* __restrict__ TS) {
    int g = blockIdx.x * 256 + threadIdx.x;           // 4*1024 threads
    int b = g >> 10, e = g & 1023;
    float acc = 0.f;
    TS[(size_t)(b * 17 + 16) * 1024 + e] = 0.f;
    for (int jt = 15; jt >= 0; jt--) {
        acc += TSpart[(size_t)(b * 16 + jt) * 1024 + e];
        TS[(size_t)(b * 17 + jt) * 1024 + e] = acc;   // sum over j >= jt*128
    }
}

// ---------------------------------------------------------------- S -> P kernel (BM=64, dbuf, FULL UNROLL)
// grid.x = 272 (136 triangular pairs x 2 halves), big-qt first
__global__ __launch_bounds__(256, 3) void k_pk(const short* __restrict__ qm,
                                               const short* __restrict__ km,
                                               short* __restrict__ P,
                                               float* __restrict__ rowsum) {
    int flip = 271 - blockIdx.x, b = blockIdx.z;
    int half = flip & 1, pidx = flip >> 1;
    int qt = 0;
    while ((qt + 1) * (qt + 2) / 2 <= pidx) qt++;
    int kt = pidx - qt * (qt + 1) / 2;
    int r0 = qt * 128 + half * 64;                       // first q-row of this block
    const short* Ag = qm + ((size_t)b * 2048 + r0) * 1024;            // 64 rows
    const short* Bg = km + ((size_t)b * 2048 + (size_t)kt * 128) * 1024; // 128 rows
    __shared__ __align__(16) short SH[24576];            // A dbuf 2x8KB | B dbuf 2x16KB
    int tid = threadIdx.x, lane = tid & 63, wave = tid >> 6;
    int wm = (wave >> 1) * 32, wn = (wave & 1) * 64;
    int lr = lane & 15, lq = lane >> 4;
    v4f acc[2][4];
    for (int i = 0; i < 2; i++) for (int j = 0; j < 4; j++) acc[i][j] = (v4f){0.f,0.f,0.f,0.f};

    stage_tile64(Ag, 1024, SH, tid);
    stage_tile(Bg, 1024, SH + 8192, tid);
    #pragma unroll
    for (int it = 0; it < 16; ++it) {
        __syncthreads();
        short* Ac = SH + (it & 1) * 4096;
        short* Bc = SH + 8192 + (it & 1) * 8192;
        if (it + 1 < 16) {
            stage_tile64(Ag + (it + 1) * 64, 1024, SH + ((it + 1) & 1) * 4096, tid);
            stage_tile  (Bg + (it + 1) * 64, 1024, SH + 8192 + ((it + 1) & 1) * 8192, tid);
        }
        COMPUTE_TILE64(Ac, Bc);
    }
    short* Pb = P + ((size_t)b << 22);
    float rs[2][4];
    for (int i = 0; i < 2; i++) for (int r = 0; r < 4; r++) rs[i][r] = 0.f;
    #pragma unroll
    for (int i = 0; i < 2; i++)
        #pragma unroll
        for (int j = 0; j < 4; j++)
            #pragma unroll
            for (int r = 0; r < 4; r++) {
                int qi = r0 + wm + i*16 + lq*4 + r;
                int kj = kt * 128 + wn + j*16 + lr;
                float p = (kj <= qi) ? __expf(acc[i][j][r] * SCALE) : 1.0f;
                Pb[(size_t)qi * 2048 + kj] = f2bf(p);
                rs[i][r] += p;
            }
    #pragma unroll
    for (int m = 1; m < 16; m <<= 1)
        #pragma unroll
        for (int i = 0; i < 2; i++)
            #pragma unroll
            for (int r = 0; r < 4; r++) rs[i][r] += __shfl_xor(rs[i][r], m);
    if (lr == 0)
        #pragma unroll
        for (int i = 0; i < 2; i++)
            #pragma unroll
            for (int r = 0; r < 4; r++)
                atomicAdd(&rowsum[b * 2048 + r0 + wm + i*16 + lq*4 + r], rs[i][r]);
}

// ---------------------------------------------------------------- PV kernel (BM=64, paired qt, 34 iters, UNROLL 2)
// grid = (8 et, 16 = 8 pairs x 2 halves, 4 b): 512 uniform blocks
__global__ __launch_bounds__(256, 3) void k_pv(const short* __restrict__ P,
                                               const short* __restrict__ vt,
                                               const float* __restrict__ rowsum,
                                               const float* __restrict__ TS,
                                               float* __restrict__ out) {
    int et = blockIdx.x, p = blockIdx.y >> 1, half = blockIdx.y & 1, b = blockIdx.z;
    const short* Bg = vt + ((size_t)b << 21) + (size_t)et * 128 * 2048;  // 128 e-rows, ld 2048
    __shared__ __align__(16) short SH[24576];            // A dbuf 2x8KB | B dbuf 2x16KB
    int tid = threadIdx.x, lane = tid & 63, wave = tid >> 6;
    int wm = (wave >> 1) * 32, wn = (wave & 1) * 64;
    int lr = lane & 15, lq = lane >> 4;

    #pragma unroll
    for (int ph = 0; ph < 2; ph++) {
        int qt = ph ? p : 15 - p;              // iters: 2(16-p) + 2(p+1) = 34 for all blocks
        int r0 = qt * 128 + half * 64;
        int iters = 2 * (qt + 1);              // always even
        const short* Ag = P + ((size_t)b << 22) + (size_t)r0 * 2048;   // 64 rows, ld 2048
        v4f acc[2][4];
        for (int i = 0; i < 2; i++) for (int j = 0; j < 4; j++) acc[i][j] = (v4f){0.f,0.f,0.f,0.f};

        stage_tile64(Ag, 2048, SH, tid);
        stage_tile(Bg, 2048, SH + 8192, tid);
        for (int it = 0; it < iters; it += 2) {
            // ---- even sub-iter: buffers 0, prefetch into buffers 1
            __syncthreads();
            if (it + 1 < iters) {
                stage_tile64(Ag + (it + 1) * 64, 2048, SH + 4096, tid);
                stage_tile  (Bg + (it + 1) * 64, 2048, SH + 8192 + 8192, tid);
            }
            COMPUTE_TILE64(SH, SH + 8192);
            // ---- odd sub-iter: buffers 1, prefetch into buffers 0
            __syncthreads();
            if (it + 2 < iters) {
                stage_tile64(Ag + (it + 2) * 64, 2048, SH, tid);
                stage_tile  (Bg + (it + 2) * 64, 2048, SH + 8192, tid);
            }
            COMPUTE_TILE64(SH + 4096, SH + 8192 + 8192);
        }
        const float* tsrow = TS + (size_t)(b * 17 + qt + 1) * 1024;
        #pragma unroll
        for (int i = 0; i < 2; i++)
            #pragma unroll
            for (int j = 0; j < 4; j++)
                #pragma unroll
                for (int r = 0; r < 4; r++) {
                    int row = r0 + wm + i*16 + lq*4 + r;
                    int col = et * 128 + wn + j*16 + lr;
                    float o = (acc[i][j][r] + tsrow[col]) / rowsum[b * 2048 + row];
                    out[((size_t)(b * 2048 + row) << 10) + col] = o;
                }
        __syncthreads();   // protect LDS before next phase's initial staging
    }
}

// ---------------------------------------------------------------- launch
extern "C" void kernel_launch(void* const* d_in, const int* in_sizes, int n_in,
                              void* d_out, int out_size, void* d_ws, size_t ws_size,
                              hipStream_t stream) {
    const float* x  = (const float*)d_in[0];
    const float* Wq = (const float*)d_in[1];
    const float* Wk = (const float*)d_in[2];
    const float* Wv = (const float*)d_in[3];
    float* out = (float*)d_out;
    char* ws = (char*)d_ws;

    short* xb     = (short*)(ws + 0);            // 16,777,216 B
    short* wb     = (short*)(ws + 16777216);     //  6,291,456 B (Wq|Wk|Wv bf16)
    short* q      = (short*)(ws + 23068672);     // 16,777,216 B
    short* k      = (short*)(ws + 39845888);     // 16,777,216 B
    short* vt     = (short*)(ws + 56623104);     // 16,777,216 B  v transposed [b][e][t]
    short* P      = (short*)(ws + 73400320);     // 33,554,432 B
    float* rowsum = (float*)(ws + 106954752);    //     32,768 B
    float* TSpart = (float*)(ws + 106987520);    //    262,144 B
    float* TS     = (float*)(ws + 107249664);    //    278,528 B   total ~102.6 MB

    k_convert<<<11264, 256, 0, stream>>>(x, Wq, Wk, Wv, xb, rowsum);
    k_qkv<<<dim3(768, 1, 1), 512, 0, stream>>>(xb, wb, q, k, vt);
    k_ts1<<<256, 256, 0, stream>>>(vt, TSpart);
    k_ts2<<<16, 256, 0, stream>>>(TSpart, TS);
    k_pk<<<dim3(272, 1, 4), 256, 0, stream>>>(q, k, P, rowsum);
    k_pv<<<dim3(8, 16, 4), 256, 0, stream>>>(P, vt, rowsum, TS, out);
}